// Round 9
// baseline (113.051 us; speedup 1.0000x reference)
//
#include <hip/hip_runtime.h>
#include <math.h>

// FocalLoss (sigmoid focal, mean reduction) — R9.
//   cls_score: [N=4, C=19, H=512, W=512] float32  (76 MiB, streamed once)
//   label:     [N=4, H=512, W=512] int32          (4 MiB, re-read 19x, cache-hot)
//
// R8 (22.55 us) = persistent grid-stride, unroll-2, PWL softplus table in LDS
// (0 trans ops/element). R9 single change: fuse the finalize into the partial
// kernel via the last-block atomic-counter pattern (validated in R2,
// absmax 0.0) — removes the second dispatch and its inter-kernel gap.

#define NC 19
#define IGNORE_INDEX 255
#define ALPHA 0.25f

typedef float f32x4 __attribute__((ext_vector_type(4)));
typedef int   i32x4 __attribute__((ext_vector_type(4)));

constexpr int NBATCH = 4;
constexpr int HW = 512 * 512;                       // 2^18
constexpr int NQ = NBATCH * NC * (HW / 4);          // 4,980,736 float4-quads
constexpr int BLOCK = 256;
constexpr int GRID = 2048;                          // 8 blocks/CU
constexpr int TT = GRID * BLOCK;                    // 524,288 threads
constexpr float INV_TOTAL = 1.0f / (float)(NBATCH * NC * HW);

constexpr int   TSEG  = 256;                        // table segments
constexpr float TMAX  = 6.0f;
constexpr float TSCALE = (float)TSEG / TMAX;        // u -> segment coord
constexpr float TH     = TMAX / (float)TSEG;        // segment width
constexpr float UCLAMP = 5.9999f;                   // keeps idx <= 255

__device__ __forceinline__ float block_reduce(float v, float* smem) {
    #pragma unroll
    for (int off = 32; off > 0; off >>= 1)
        v += __shfl_down(v, off, 64);
    const int lane = threadIdx.x & 63;
    const int wid  = threadIdx.x >> 6;
    if (lane == 0) smem[wid] = v;
    __syncthreads();
    float s = 0.0f;
    if (threadIdx.x == 0) {
        #pragma unroll
        for (int i = 0; i < BLOCK / 64; ++i) s += smem[i];
    }
    return s;  // valid in thread 0 only
}

__device__ __forceinline__ float quad_loss(const f32x4 v, const i32x4 l4,
                                           const int c, const float2* tab) {
    float acc = 0.0f;
    #pragma unroll
    for (int j = 0; j < 4; ++j) {
        const float xv  = v[j];
        const int   lb  = l4[j];
        const bool  val = (lb >= 0) && (lb != IGNORE_INDEX);
        const bool  t   = (lb == c);

        // q(|x|) = log1p(exp(-|x|)) via PWL table (secant interp)
        const float uc = fminf(fabsf(xv), UCLAMP);
        const float g  = uc * TSCALE;
        const int   ii = (int)g;                    // trunc == floor (g>=0)
        const float fr = g - (float)ii;
        const float2 ab = tab[ii];
        const float sp  = fmaf(ab.y, fr, ab.x);

        const float y   = t ? -xv : xv;
        const float d   = y + (t ? 1.0f : 0.0f);    // t? 1-x : x
        const float w   = (val ? ALPHA : 0.0f) * d * d;
        const float bce = fmaxf(y, 0.0f) + sp;      // = max(x,0)-x*t+q(|x|)
        acc = fmaf(bce, w, acc);
    }
    return acc;
}

__global__ __launch_bounds__(BLOCK, 8) void focal_fused(
        const f32x4*  __restrict__ x,
        const i32x4*  __restrict__ lab4,
        float*        __restrict__ partial,
        unsigned int* __restrict__ counter,
        float*        __restrict__ out) {
    __shared__ float2 tab[TSEG];
    {
        const int i  = threadIdx.x;                 // BLOCK == TSEG
        const float u0 = (float)i * TH;
        const float q0 = log1pf(__expf(-u0));
        const float q1 = log1pf(__expf(-(u0 + TH)));
        tab[i] = make_float2(q0, q1 - q0);
    }
    __syncthreads();

    const int tid = blockIdx.x * BLOCK + threadIdx.x;

    float acc = 0.0f;
    for (int q = tid; q < NQ; q += 2 * TT) {
        const unsigned plane0 = (unsigned)q >> 16;
        const int      pixq0  = q & 65535;
        const unsigned n0     = plane0 / NC;        // magic-mul div
        const int      c0     = (int)(plane0 - n0 * NC);
        const f32x4    v0     = __builtin_nontemporal_load(x + q);
        const i32x4    l0     = lab4[((size_t)n0 << 16) + pixq0];

        const int q1i = q + TT;
        if (q1i < NQ) {
            const unsigned plane1 = (unsigned)q1i >> 16;
            const int      pixq1  = q1i & 65535;
            const unsigned n1     = plane1 / NC;
            const int      c1     = (int)(plane1 - n1 * NC);
            const f32x4    v1     = __builtin_nontemporal_load(x + q1i);
            const i32x4    l1     = lab4[((size_t)n1 << 16) + pixq1];
            acc += quad_loss(v0, l0, c0, tab);
            acc += quad_loss(v1, l1, c1, tab);
        } else {
            acc += quad_loss(v0, l0, c0, tab);
        }
    }

    __shared__ float smem[BLOCK / 64];
    const float s = block_reduce(acc, smem);

    __shared__ bool is_last;
    if (threadIdx.x == 0) {
        partial[blockIdx.x] = s;
        __threadfence();                            // release partial
        const unsigned int old = atomicAdd(counter, 1u);
        is_last = (old == GRID - 1);
    }
    __syncthreads();

    if (is_last) {
        __threadfence();                            // acquire all partials
        float a2 = 0.0f;
        for (int i = threadIdx.x; i < GRID; i += BLOCK)
            a2 += partial[i];
        const float s2 = block_reduce(a2, smem);
        if (threadIdx.x == 0) out[0] = s2 * INV_TOTAL;  // LOSS_WEIGHT == 1.0
    }
}

extern "C" void kernel_launch(void* const* d_in, const int* in_sizes, int n_in,
                              void* d_out, int out_size, void* d_ws, size_t ws_size,
                              hipStream_t stream) {
    const f32x4* cls_score = (const f32x4*)d_in[0];
    const i32x4* lab4      = (const i32x4*)d_in[1];
    float* out      = (float*)d_out;
    float* partial  = (float*)d_ws;                           // GRID floats
    unsigned int* counter = (unsigned int*)((char*)d_ws + GRID * sizeof(float));

    hipMemsetAsync(counter, 0, sizeof(unsigned int), stream);
    focal_fused<<<GRID, BLOCK, 0, stream>>>(cls_score, lab4, partial, counter, out);
}

// Round 10
// 22.232 us; speedup vs baseline: 5.0850x; 5.0850x over previous
//
#include <hip/hip_runtime.h>
#include <math.h>

// FocalLoss (sigmoid focal, mean reduction) — R10.
//   cls_score: [N=4, C=19, H=512, W=512] float32  (76 MiB, streamed once)
//   label:     [N=4, H=512, W=512] int32          (4 MiB, re-read 19x, cache-hot)
//
// Structure lessons (measured):
//  - NEVER fuse the last-block tail: R2/R7/R9 all collapsed to ~20-36 VGPR
//    serialized main loops (tail perturbs regalloc) -> 100+ us. Two kernels.
//  - R8 (22.55us): PWL softplus table kills the 16us trans-pipe floor. Keep.
//  - Remaining gap is load-side MLP: R8 keeps ~64 B/lane in flight.
// R10: 8 quads/thread (2432 blocks x 256 thr, exact tiling, no guards).
// All 16 loads (8 cls f32x4 + 8 label i32x4 = 256 B/lane) issued back-to-back,
// then pinned live with an empty asm "+v" clamp so hipcc cannot serialize
// them (the R7/R9 failure mode). One vmcnt wait, then 32 elements of compute.
// __launch_bounds__(256,4): 128-VGPR cap, 16 waves/CU.

#define NC 19
#define IGNORE_INDEX 255
#define ALPHA 0.25f

typedef float f32x4 __attribute__((ext_vector_type(4)));
typedef int   i32x4 __attribute__((ext_vector_type(4)));

constexpr int NBATCH = 4;
constexpr int HW = 512 * 512;                       // 2^18
constexpr int NQ = NBATCH * NC * (HW / 4);          // 4,980,736 float4-quads
constexpr int BLOCK = 256;
constexpr int QPT = 8;                              // quads per thread
constexpr int GRID = NQ / (BLOCK * QPT);            // 2432, exact
constexpr int TT = GRID * BLOCK;                    // 622,592 threads (stride)
constexpr int BLOCK2 = 1024;
constexpr float INV_TOTAL = 1.0f / (float)(NBATCH * NC * HW);

constexpr int   TSEG  = 256;
constexpr float TMAX  = 6.0f;
constexpr float TSCALE = (float)TSEG / TMAX;
constexpr float TH     = TMAX / (float)TSEG;
constexpr float UCLAMP = 5.9999f;

template <int NWAVE>
__device__ __forceinline__ float block_reduce(float v, float* smem) {
    #pragma unroll
    for (int off = 32; off > 0; off >>= 1)
        v += __shfl_down(v, off, 64);
    const int lane = threadIdx.x & 63;
    const int wid  = threadIdx.x >> 6;
    if (lane == 0) smem[wid] = v;
    __syncthreads();
    float s = 0.0f;
    if (threadIdx.x == 0) {
        #pragma unroll
        for (int i = 0; i < NWAVE; ++i) s += smem[i];
    }
    return s;  // valid in thread 0 only
}

__device__ __forceinline__ float quad_loss(const f32x4 v, const i32x4 l4,
                                           const int c, const float2* tab) {
    float acc = 0.0f;
    #pragma unroll
    for (int j = 0; j < 4; ++j) {
        const float xv  = v[j];
        const int   lb  = l4[j];
        const bool  val = (lb >= 0) && (lb != IGNORE_INDEX);
        const bool  t   = (lb == c);

        // q(|x|) = log1p(exp(-|x|)) via PWL table (secant interp)
        const float uc = fminf(fabsf(xv), UCLAMP);
        const float g  = uc * TSCALE;
        const int   ii = (int)g;
        const float fr = g - (float)ii;
        const float2 ab = tab[ii];
        const float sp  = fmaf(ab.y, fr, ab.x);

        const float y   = t ? -xv : xv;
        const float d   = y + (t ? 1.0f : 0.0f);    // t? 1-x : x
        const float w   = (val ? ALPHA : 0.0f) * d * d;
        const float bce = fmaxf(y, 0.0f) + sp;      // = max(x,0)-x*t+q(|x|)
        acc = fmaf(bce, w, acc);
    }
    return acc;
}

__global__ __launch_bounds__(BLOCK, 4) void focal_partial(
        const f32x4* __restrict__ x,
        const i32x4* __restrict__ lab4,
        float*       __restrict__ partial) {
    __shared__ float2 tab[TSEG];
    {
        const int i  = threadIdx.x;                 // BLOCK == TSEG
        const float u0 = (float)i * TH;
        const float q0 = log1pf(__expf(-u0));
        const float q1 = log1pf(__expf(-(u0 + TH)));
        tab[i] = make_float2(q0, q1 - q0);
    }
    __syncthreads();

    const int tid = blockIdx.x * BLOCK + threadIdx.x;

    // Per-quad indices & class ids (q_k = tid + k*TT, exact, no guards).
    int c_[QPT];
    int li_[QPT];
    #pragma unroll
    for (int k = 0; k < QPT; ++k) {
        const int      q     = tid + k * TT;
        const unsigned plane = (unsigned)q >> 16;
        const unsigned n     = plane / NC;          // magic-mul div
        c_[k]  = (int)(plane - n * NC);
        li_[k] = (int)((n << 16) + (q & 65535));
    }

    // Issue all 16 loads back-to-back, then pin them live so the compiler
    // cannot interleave/serialize (R7/R9 failure mode): 256 B/lane in flight.
    f32x4 v0 = x[tid + 0 * TT], v1 = x[tid + 1 * TT],
          v2 = x[tid + 2 * TT], v3 = x[tid + 3 * TT],
          v4 = x[tid + 4 * TT], v5 = x[tid + 5 * TT],
          v6 = x[tid + 6 * TT], v7 = x[tid + 7 * TT];
    i32x4 l0 = lab4[li_[0]], l1 = lab4[li_[1]],
          l2 = lab4[li_[2]], l3 = lab4[li_[3]],
          l4 = lab4[li_[4]], l5 = lab4[li_[5]],
          l6 = lab4[li_[6]], l7 = lab4[li_[7]];
    asm volatile("" : "+v"(v0), "+v"(v1), "+v"(v2), "+v"(v3),
                      "+v"(v4), "+v"(v5), "+v"(v6), "+v"(v7),
                      "+v"(l0), "+v"(l1), "+v"(l2), "+v"(l3),
                      "+v"(l4), "+v"(l5), "+v"(l6), "+v"(l7));

    float acc = quad_loss(v0, l0, c_[0], tab);
    acc += quad_loss(v1, l1, c_[1], tab);
    acc += quad_loss(v2, l2, c_[2], tab);
    acc += quad_loss(v3, l3, c_[3], tab);
    acc += quad_loss(v4, l4, c_[4], tab);
    acc += quad_loss(v5, l5, c_[5], tab);
    acc += quad_loss(v6, l6, c_[6], tab);
    acc += quad_loss(v7, l7, c_[7], tab);

    __shared__ float smem[BLOCK / 64];
    const float s = block_reduce<BLOCK / 64>(acc, smem);
    if (threadIdx.x == 0) partial[blockIdx.x] = s;
}

__global__ __launch_bounds__(BLOCK2) void focal_finalize(
        const float* __restrict__ partial,
        float*       __restrict__ out) {
    float acc = 0.0f;
    for (int i = threadIdx.x; i < GRID; i += BLOCK2)
        acc += partial[i];
    __shared__ float smem[BLOCK2 / 64];
    const float s = block_reduce<BLOCK2 / 64>(acc, smem);
    if (threadIdx.x == 0) out[0] = s * INV_TOTAL;  // LOSS_WEIGHT == 1.0
}

extern "C" void kernel_launch(void* const* d_in, const int* in_sizes, int n_in,
                              void* d_out, int out_size, void* d_ws, size_t ws_size,
                              hipStream_t stream) {
    const f32x4* cls_score = (const f32x4*)d_in[0];
    const i32x4* lab4      = (const i32x4*)d_in[1];
    float* out     = (float*)d_out;
    float* partial = (float*)d_ws;   // GRID floats

    focal_partial<<<GRID, BLOCK, 0, stream>>>(cls_score, lab4, partial);
    focal_finalize<<<1, BLOCK2, 0, stream>>>(partial, out);
}

// Round 11
// 21.427 us; speedup vs baseline: 5.2760x; 1.0376x over previous
//
#include <hip/hip_runtime.h>

// FocalLoss (sigmoid focal, mean reduction) — R11.
//   cls_score: [N=4, C=19, H=512, W=512] float32  (76 MiB, streamed once)
//   label:     [N=4, H=512, W=512] int32          (4 MiB, re-read 19x, cache-hot)
//
// Structure lessons (measured):
//  - NEVER fuse the last-block tail (R2/R7/R9: tail perturbs regalloc ->
//    20-36 VGPR serialized main loop -> 100+ us). Two kernels.
//  - R8: replacing v_exp+v_log with table = -3 us (trans pipe ~3 us, not 16).
//  - R10: deep-MLP pin = null; load issue structure is not the constraint.
// R11 single lever: drop the LDS table (R9 showed 895K bank-conflict cycles
// from the random 64-lane float2 gather). softplus q(u)=log1p(exp(-u)) via a
// degree-6 Chebyshev polynomial on [0,6] (max err ~3.5e-4; output bias after
// 0.25*d^2 weighting and 20M-element mean < 1e-4, threshold 5.5e-3).
// Inner loop now touches NO LDS: pure FMA chain.

#define NC 19
#define IGNORE_INDEX 255
#define ALPHA 0.25f

typedef float f32x4 __attribute__((ext_vector_type(4)));
typedef int   i32x4 __attribute__((ext_vector_type(4)));

constexpr int NBATCH = 4;
constexpr int HW = 512 * 512;                       // 2^18
constexpr int NQ = NBATCH * NC * (HW / 4);          // 4,980,736 float4-quads
constexpr int BLOCK = 256;
constexpr int QPT = 8;                              // quads per thread
constexpr int GRID = NQ / (BLOCK * QPT);            // 2432, exact
constexpr int TT = GRID * BLOCK;                    // 622,592 (stride)
constexpr int BLOCK2 = 1024;
constexpr float INV_TOTAL = 1.0f / (float)(NBATCH * NC * HW);

// Chebyshev-interpolant (7 nodes) of log1p(exp(-u)) on u in [0,6],
// expressed in monomials of x = u/3 - 1, x in [-1,1]. Max err ~3.5e-4.
constexpr float A0 =  0.0485865f;
constexpr float A1 = -0.1402039f;
constexpr float A2 =  0.2024491f;
constexpr float A3 = -0.2005852f;
constexpr float A4 =  0.1182934f;
constexpr float A5 = -0.0048016f;
constexpr float A6 = -0.0214538f;

template <int NWAVE>
__device__ __forceinline__ float block_reduce(float v, float* smem) {
    #pragma unroll
    for (int off = 32; off > 0; off >>= 1)
        v += __shfl_down(v, off, 64);
    const int lane = threadIdx.x & 63;
    const int wid  = threadIdx.x >> 6;
    if (lane == 0) smem[wid] = v;
    __syncthreads();
    float s = 0.0f;
    if (threadIdx.x == 0) {
        #pragma unroll
        for (int i = 0; i < NWAVE; ++i) s += smem[i];
    }
    return s;  // valid in thread 0 only
}

__device__ __forceinline__ float quad_loss(const f32x4 v, const i32x4 l4,
                                           const int c) {
    float acc = 0.0f;
    #pragma unroll
    for (int j = 0; j < 4; ++j) {
        const float xv  = v[j];
        const int   lb  = l4[j];
        const bool  val = (lb >= 0) && (lb != IGNORE_INDEX);
        const bool  t   = (lb == c);

        // softplus q(|x|) via degree-6 polynomial, no LDS, no trans.
        const float u  = fminf(fabsf(xv), 6.0f);
        const float xx = fmaf(u, 0.33333333f, -1.0f);
        float sp = A6;
        sp = fmaf(sp, xx, A5);
        sp = fmaf(sp, xx, A4);
        sp = fmaf(sp, xx, A3);
        sp = fmaf(sp, xx, A2);
        sp = fmaf(sp, xx, A1);
        sp = fmaf(sp, xx, A0);

        const float y   = t ? -xv : xv;
        const float d   = y + (t ? 1.0f : 0.0f);    // t? 1-x : x
        const float w   = (val ? ALPHA : 0.0f) * d * d;
        const float bce = fmaxf(y, 0.0f) + sp;      // = max(x,0)-x*t+q(|x|)
        acc = fmaf(bce, w, acc);
    }
    return acc;
}

__global__ __launch_bounds__(BLOCK, 4) void focal_partial(
        const f32x4* __restrict__ x,
        const i32x4* __restrict__ lab4,
        float*       __restrict__ partial) {
    const int tid = blockIdx.x * BLOCK + threadIdx.x;

    // Per-quad class ids / label indices (q_k = tid + k*TT, exact tiling).
    int c_[QPT];
    int li_[QPT];
    #pragma unroll
    for (int k = 0; k < QPT; ++k) {
        const int      q     = tid + k * TT;
        const unsigned plane = (unsigned)q >> 16;
        const unsigned n     = plane / NC;          // magic-mul div
        c_[k]  = (int)(plane - n * NC);
        li_[k] = (int)((n << 16) + (q & 65535));
    }

    // Issue all 16 loads back-to-back; pin live (R7/R9 serialization guard).
    f32x4 v0 = x[tid + 0 * TT], v1 = x[tid + 1 * TT],
          v2 = x[tid + 2 * TT], v3 = x[tid + 3 * TT],
          v4 = x[tid + 4 * TT], v5 = x[tid + 5 * TT],
          v6 = x[tid + 6 * TT], v7 = x[tid + 7 * TT];
    i32x4 l0 = lab4[li_[0]], l1 = lab4[li_[1]],
          l2 = lab4[li_[2]], l3 = lab4[li_[3]],
          l4 = lab4[li_[4]], l5 = lab4[li_[5]],
          l6 = lab4[li_[6]], l7 = lab4[li_[7]];
    asm volatile("" : "+v"(v0), "+v"(v1), "+v"(v2), "+v"(v3),
                      "+v"(v4), "+v"(v5), "+v"(v6), "+v"(v7),
                      "+v"(l0), "+v"(l1), "+v"(l2), "+v"(l3),
                      "+v"(l4), "+v"(l5), "+v"(l6), "+v"(l7));

    float acc = quad_loss(v0, l0, c_[0]);
    acc += quad_loss(v1, l1, c_[1]);
    acc += quad_loss(v2, l2, c_[2]);
    acc += quad_loss(v3, l3, c_[3]);
    acc += quad_loss(v4, l4, c_[4]);
    acc += quad_loss(v5, l5, c_[5]);
    acc += quad_loss(v6, l6, c_[6]);
    acc += quad_loss(v7, l7, c_[7]);

    __shared__ float smem[BLOCK / 64];
    const float s = block_reduce<BLOCK / 64>(acc, smem);
    if (threadIdx.x == 0) partial[blockIdx.x] = s;
}

__global__ __launch_bounds__(BLOCK2) void focal_finalize(
        const float* __restrict__ partial,
        float*       __restrict__ out) {
    float acc = 0.0f;
    for (int i = threadIdx.x; i < GRID; i += BLOCK2)
        acc += partial[i];
    __shared__ float smem[BLOCK2 / 64];
    const float s = block_reduce<BLOCK2 / 64>(acc, smem);
    if (threadIdx.x == 0) out[0] = s * INV_TOTAL;  // LOSS_WEIGHT == 1.0
}

extern "C" void kernel_launch(void* const* d_in, const int* in_sizes, int n_in,
                              void* d_out, int out_size, void* d_ws, size_t ws_size,
                              hipStream_t stream) {
    const f32x4* cls_score = (const f32x4*)d_in[0];
    const i32x4* lab4      = (const i32x4*)d_in[1];
    float* out     = (float*)d_out;
    float* partial = (float*)d_ws;   // GRID floats

    focal_partial<<<GRID, BLOCK, 0, stream>>>(cls_score, lab4, partial);
    focal_finalize<<<1, BLOCK2, 0, stream>>>(partial, out);
}

// Round 12
// 21.202 us; speedup vs baseline: 5.3321x; 1.0106x over previous
//
#include <hip/hip_runtime.h>

// FocalLoss (sigmoid focal, mean reduction) — R12.
//   cls_score: [N=4, C=19, H=512, W=512] float32  (76 MiB, streamed once)
//   label:     [N=4, H=512, W=512] int32          (4 MiB, re-read 19x, cache-hot)
//
// Structure lessons (measured):
//  - NEVER fuse the last-block tail (R2/R7/R9: regalloc collapse -> 100+ us).
//  - R8: PWL table -3 us (trans pipe). R11: poly softplus -0.8 us (LDS gone).
//  - R10 (QPT=8, 4 waves/SIMD): null vs R8 -> ILP-for-occupancy trade was flat.
// R12 lever: occupancy. QPT 8->4 (8 loads, 128 B/lane in flight),
// __launch_bounds__(256,8) -> <=64 VGPR -> 8 waves/SIMD resident;
// GRID=4864 (19 waves/SIMD of work) smooths block turnover.

#define NC 19
#define IGNORE_INDEX 255
#define ALPHA 0.25f

typedef float f32x4 __attribute__((ext_vector_type(4)));
typedef int   i32x4 __attribute__((ext_vector_type(4)));

constexpr int NBATCH = 4;
constexpr int HW = 512 * 512;                       // 2^18
constexpr int NQ = NBATCH * NC * (HW / 4);          // 4,980,736 float4-quads
constexpr int BLOCK = 256;
constexpr int QPT = 4;                              // quads per thread
constexpr int GRID = NQ / (BLOCK * QPT);            // 4864, exact
constexpr int TT = GRID * BLOCK;                    // 1,245,184 (stride)
constexpr int BLOCK2 = 1024;
constexpr float INV_TOTAL = 1.0f / (float)(NBATCH * NC * HW);

// Chebyshev-interpolant (7 nodes) of log1p(exp(-u)) on u in [0,6],
// monomials of x = u/3 - 1. Max err ~3.5e-4 (<< 5.5e-3 threshold).
constexpr float A0 =  0.0485865f;
constexpr float A1 = -0.1402039f;
constexpr float A2 =  0.2024491f;
constexpr float A3 = -0.2005852f;
constexpr float A4 =  0.1182934f;
constexpr float A5 = -0.0048016f;
constexpr float A6 = -0.0214538f;

template <int NWAVE>
__device__ __forceinline__ float block_reduce(float v, float* smem) {
    #pragma unroll
    for (int off = 32; off > 0; off >>= 1)
        v += __shfl_down(v, off, 64);
    const int lane = threadIdx.x & 63;
    const int wid  = threadIdx.x >> 6;
    if (lane == 0) smem[wid] = v;
    __syncthreads();
    float s = 0.0f;
    if (threadIdx.x == 0) {
        #pragma unroll
        for (int i = 0; i < NWAVE; ++i) s += smem[i];
    }
    return s;  // valid in thread 0 only
}

__device__ __forceinline__ float quad_loss(const f32x4 v, const i32x4 l4,
                                           const int c) {
    float acc = 0.0f;
    #pragma unroll
    for (int j = 0; j < 4; ++j) {
        const float xv  = v[j];
        const int   lb  = l4[j];
        const bool  val = (lb >= 0) && (lb != IGNORE_INDEX);
        const bool  t   = (lb == c);

        // softplus q(|x|) via degree-6 polynomial, no LDS, no trans.
        const float u  = fminf(fabsf(xv), 6.0f);
        const float xx = fmaf(u, 0.33333333f, -1.0f);
        float sp = A6;
        sp = fmaf(sp, xx, A5);
        sp = fmaf(sp, xx, A4);
        sp = fmaf(sp, xx, A3);
        sp = fmaf(sp, xx, A2);
        sp = fmaf(sp, xx, A1);
        sp = fmaf(sp, xx, A0);

        const float y   = t ? -xv : xv;
        const float d   = y + (t ? 1.0f : 0.0f);    // t? 1-x : x
        const float w   = (val ? ALPHA : 0.0f) * d * d;
        const float bce = fmaxf(y, 0.0f) + sp;      // = max(x,0)-x*t+q(|x|)
        acc = fmaf(bce, w, acc);
    }
    return acc;
}

__global__ __launch_bounds__(BLOCK, 8) void focal_partial(
        const f32x4* __restrict__ x,
        const i32x4* __restrict__ lab4,
        float*       __restrict__ partial) {
    const int tid = blockIdx.x * BLOCK + threadIdx.x;

    // Per-quad class ids / label indices (q_k = tid + k*TT, exact tiling).
    int c_[QPT];
    int li_[QPT];
    #pragma unroll
    for (int k = 0; k < QPT; ++k) {
        const int      q     = tid + k * TT;
        const unsigned plane = (unsigned)q >> 16;
        const unsigned n     = plane / NC;          // magic-mul div
        c_[k]  = (int)(plane - n * NC);
        li_[k] = (int)((n << 16) + (q & 65535));
    }

    // Issue all 8 loads back-to-back; pin live (R7/R9 serialization guard).
    f32x4 v0 = x[tid + 0 * TT], v1 = x[tid + 1 * TT],
          v2 = x[tid + 2 * TT], v3 = x[tid + 3 * TT];
    i32x4 l0 = lab4[li_[0]], l1 = lab4[li_[1]],
          l2 = lab4[li_[2]], l3 = lab4[li_[3]];
    asm volatile("" : "+v"(v0), "+v"(v1), "+v"(v2), "+v"(v3),
                      "+v"(l0), "+v"(l1), "+v"(l2), "+v"(l3));

    float acc = quad_loss(v0, l0, c_[0]);
    acc += quad_loss(v1, l1, c_[1]);
    acc += quad_loss(v2, l2, c_[2]);
    acc += quad_loss(v3, l3, c_[3]);

    __shared__ float smem[BLOCK / 64];
    const float s = block_reduce<BLOCK / 64>(acc, smem);
    if (threadIdx.x == 0) partial[blockIdx.x] = s;
}

__global__ __launch_bounds__(BLOCK2) void focal_finalize(
        const float* __restrict__ partial,
        float*       __restrict__ out) {
    float acc = 0.0f;
    for (int i = threadIdx.x; i < GRID; i += BLOCK2)
        acc += partial[i];
    __shared__ float smem[BLOCK2 / 64];
    const float s = block_reduce<BLOCK2 / 64>(acc, smem);
    if (threadIdx.x == 0) out[0] = s * INV_TOTAL;  // LOSS_WEIGHT == 1.0
}

extern "C" void kernel_launch(void* const* d_in, const int* in_sizes, int n_in,
                              void* d_out, int out_size, void* d_ws, size_t ws_size,
                              hipStream_t stream) {
    const f32x4* cls_score = (const f32x4*)d_in[0];
    const i32x4* lab4      = (const i32x4*)d_in[1];
    float* out     = (float*)d_out;
    float* partial = (float*)d_ws;   // GRID floats

    focal_partial<<<GRID, BLOCK, 0, stream>>>(cls_score, lab4, partial);
    focal_finalize<<<1, BLOCK2, 0, stream>>>(partial, out);
}